// Round 9
// baseline (506.407 us; speedup 1.0000x reference)
//
#include <hip/hip_runtime.h>
#include <cstdint>
#include <cstddef>

#define NNODES 100000
#define DIM 128
#define WLD 136   // LDS stride (u16) for W planes

typedef unsigned short u16;
typedef __attribute__((ext_vector_type(8))) short v8s;
typedef __attribute__((ext_vector_type(4))) float v4f;

__device__ __forceinline__ float bf2f(u16 u) {
  union { uint32_t i; float f; } x; x.i = ((uint32_t)u) << 16; return x.f;
}
__device__ __forceinline__ u16 f2bf(float f) {
  union { float f; uint32_t i; } x; x.f = f;
  uint32_t r = x.i + 0x7fffu + ((x.i >> 16) & 1u);  // RNE
  return (u16)(r >> 16);
}
__device__ __forceinline__ void split2(float f, u16& hi, u16& lo) {
  u16 h = f2bf(f);
  float r = f - bf2f(h);     // exact
  hi = h;
  lo = f2bf(r);
}

// =================== unified CSR build (3 lists concatenated) ===================

__global__ void count_all(const int* __restrict__ d2u, const int* __restrict__ sle,
                          const int* __restrict__ u2d, int E1, int E2, int E3,
                          int* __restrict__ cnt) {
  int e = blockIdx.x * 256 + threadIdx.x;
  int idx;
  if (e < E1)            idx = d2u[E1 + e];
  else if (e < E1 + E2)  idx = NNODES + sle[E2 + (e - E1)];
  else if (e < E1 + E2 + E3) idx = 2 * NNODES + u2d[E3 + (e - E1 - E2)];
  else return;
  atomicAdd(&cnt[idx], 1);
}

__global__ void fill_all(const int* __restrict__ d2u, const int* __restrict__ sle,
                         const int* __restrict__ u2d, int E1, int E2, int E3,
                         const int* __restrict__ rs, int* __restrict__ fill,
                         int* __restrict__ eidx) {
  int e = blockIdx.x * 256 + threadIdx.x;
  int idx, src;
  if (e < E1)            { idx = d2u[E1 + e];                src = d2u[e]; }
  else if (e < E1 + E2)  { int q = e - E1; idx = NNODES + sle[E2 + q];     src = sle[q]; }
  else if (e < E1 + E2 + E3) { int q = e - E1 - E2; idx = 2 * NNODES + u2d[E3 + q]; src = u2d[q]; }
  else return;
  int p = rs[idx] + atomicAdd(&fill[idx], 1);
  eidx[p] = src;
}

__global__ void scan_blocks(const int* __restrict__ in, int* __restrict__ out,
                            int* __restrict__ bsum, int n) {
  __shared__ int wsum[4];
  const int tid = threadIdx.x;
  const int base = blockIdx.x * 1024 + tid * 4;
  int v0 = 0, v1 = 0, v2 = 0, v3 = 0;
  if (base + 0 < n) v0 = in[base + 0];
  if (base + 1 < n) v1 = in[base + 1];
  if (base + 2 < n) v2 = in[base + 2];
  if (base + 3 < n) v3 = in[base + 3];
  const int tsum = v0 + v1 + v2 + v3;
  const int lane = tid & 63, wid = tid >> 6;
  int x = tsum;
  for (int off = 1; off < 64; off <<= 1) {
    int y = __shfl_up(x, off, 64);
    if (lane >= off) x += y;
  }
  if (lane == 63) wsum[wid] = x;
  __syncthreads();
  int woff = 0;
  for (int w = 0; w < wid; ++w) woff += wsum[w];
  const int excl = woff + x - tsum;
  if (base + 0 < n) out[base + 0] = excl;
  if (base + 1 < n) out[base + 1] = excl + v0;
  if (base + 2 < n) out[base + 2] = excl + v0 + v1;
  if (base + 3 < n) out[base + 3] = excl + v0 + v1 + v2;
  if (tid == 255) bsum[blockIdx.x] = woff + x;
}

__global__ void scan_top(int* __restrict__ bsum, int nb) {
  __shared__ int tmp[1024];
  const int tid = threadIdx.x;
  for (int i = tid; i < 1024; i += 256) tmp[i] = (i < nb) ? bsum[i] : 0;
  __syncthreads();
  for (int off = 1; off < 1024; off <<= 1) {
    int vals[4];
#pragma unroll
    for (int j = 0; j < 4; ++j) { int i = tid + j * 256; vals[j] = (i >= off) ? tmp[i - off] : 0; }
    __syncthreads();
#pragma unroll
    for (int j = 0; j < 4; ++j) { int i = tid + j * 256; tmp[i] += vals[j]; }
    __syncthreads();
  }
  for (int i = tid; i < nb; i += 256) {
    int orig = bsum[i];
    bsum[i] = tmp[i] - orig;   // exclusive
  }
}

__global__ void scan_add(int* __restrict__ out, const int* __restrict__ bsum, int n) {
  const int b = blockIdx.x;
  const int off = bsum[b];
  const int base = b * 1024 + threadIdx.x * 4;
#pragma unroll
  for (int j = 0; j < 4; ++j)
    if (base + j < n) out[base + j] += off;
}

__global__ void make_rnorm(const int* __restrict__ cntB, float* __restrict__ rnorm, int n) {
  int i = blockIdx.x * 256 + threadIdx.x;
  if (i < n) rnorm[i] = rsqrtf((float)cntB[i] + 1.0f);
}

__global__ void make_w_planes(const float* __restrict__ W0, const float* __restrict__ W1,
                              const float* __restrict__ W2,
                              u16* __restrict__ Whi, u16* __restrict__ Wlo) {
  int i = blockIdx.x * 256 + threadIdx.x;
  if (i >= 3 * DIM * DIM) return;
  int m = i / (DIM * DIM);
  int idx = i - m * DIM * DIM;
  int k = idx >> 7, c = idx & 127;
  const float* W = (m == 0) ? W0 : ((m == 1) ? W1 : W2);
  u16 h, l;
  split2(W[idx], h, l);
  int o = m * DIM * DIM + c * DIM + k;
  Whi[o] = h;
  Wlo[o] = l;
}

// =================== gathers (32 threads / node, 4 cols each) ===================

__global__ void gather_mean_split(const float* __restrict__ x, const int* __restrict__ rs,
                                  const int* __restrict__ cnt, const int* __restrict__ eidx,
                                  u16* __restrict__ ohi, u16* __restrict__ olo, int n) {
  int gid = blockIdx.x * 256 + threadIdx.x;
  int i = gid >> 5;
  if (i >= n) return;
  int c = (gid & 31) << 2;
  int start = rs[i], m = cnt[i];
  float4 acc = {0.f, 0.f, 0.f, 0.f};
  int j = 0;
  for (; j + 1 < m; j += 2) {
    int s0 = eidx[start + j], s1 = eidx[start + j + 1];
    float4 v0 = *(const float4*)(x + (size_t)s0 * DIM + c);
    float4 v1 = *(const float4*)(x + (size_t)s1 * DIM + c);
    acc.x += v0.x + v1.x; acc.y += v0.y + v1.y;
    acc.z += v0.z + v1.z; acc.w += v0.w + v1.w;
  }
  if (j < m) {
    int s = eidx[start + j];
    float4 v = *(const float4*)(x + (size_t)s * DIM + c);
    acc.x += v.x; acc.y += v.y; acc.z += v.z; acc.w += v.w;
  }
  float inv = 1.0f / fmaxf((float)m, 1.0f);
  acc.x *= inv; acc.y *= inv; acc.z *= inv; acc.w *= inv;
  ushort4 sh, sl;
  split2(acc.x, sh.x, sl.x);
  split2(acc.y, sh.y, sl.y);
  split2(acc.z, sh.z, sl.z);
  split2(acc.w, sh.w, sl.w);
  size_t off = (size_t)i * DIM + c;
  *(ushort4*)(ohi + off) = sh;
  *(ushort4*)(olo + off) = sl;
}

__global__ void gather_gcn(const u16* __restrict__ hhi, const u16* __restrict__ hlo,
                           const int* __restrict__ rs, const int* __restrict__ cnt,
                           const int* __restrict__ eidx, const float* __restrict__ rnorm,
                           const float* __restrict__ bias, float* __restrict__ out, int n) {
  int gid = blockIdx.x * 256 + threadIdx.x;
  int i = gid >> 5;
  if (i >= n) return;
  int c = (gid & 31) << 2;
  int start = rs[i], m = cnt[i];
  float4 acc = {0.f, 0.f, 0.f, 0.f};
  int j = 0;
  for (; j + 1 < m; j += 2) {
    int s0 = eidx[start + j], s1 = eidx[start + j + 1];
    float r0 = rnorm[s0], r1 = rnorm[s1];
    size_t o0 = (size_t)s0 * DIM + c, o1 = (size_t)s1 * DIM + c;
    ushort4 h0 = *(const ushort4*)(hhi + o0), l0 = *(const ushort4*)(hlo + o0);
    ushort4 h1 = *(const ushort4*)(hhi + o1), l1 = *(const ushort4*)(hlo + o1);
    acc.x = fmaf(r0, bf2f(h0.x) + bf2f(l0.x), fmaf(r1, bf2f(h1.x) + bf2f(l1.x), acc.x));
    acc.y = fmaf(r0, bf2f(h0.y) + bf2f(l0.y), fmaf(r1, bf2f(h1.y) + bf2f(l1.y), acc.y));
    acc.z = fmaf(r0, bf2f(h0.z) + bf2f(l0.z), fmaf(r1, bf2f(h1.z) + bf2f(l1.z), acc.z));
    acc.w = fmaf(r0, bf2f(h0.w) + bf2f(l0.w), fmaf(r1, bf2f(h1.w) + bf2f(l1.w), acc.w));
  }
  if (j < m) {
    int s = eidx[start + j];
    float rn = rnorm[s];
    size_t off = (size_t)s * DIM + c;
    ushort4 vh = *(const ushort4*)(hhi + off);
    ushort4 vl = *(const ushort4*)(hlo + off);
    acc.x = fmaf(rn, bf2f(vh.x) + bf2f(vl.x), acc.x);
    acc.y = fmaf(rn, bf2f(vh.y) + bf2f(vl.y), acc.y);
    acc.z = fmaf(rn, bf2f(vh.z) + bf2f(vl.z), acc.z);
    acc.w = fmaf(rn, bf2f(vh.w) + bf2f(vl.w), acc.w);
  }
  float ri = rnorm[i];
  float invd = ri * ri;
  size_t offi = (size_t)i * DIM + c;
  ushort4 sh = *(const ushort4*)(hhi + offi);
  ushort4 sl = *(const ushort4*)(hlo + offi);
  float4 bv = *(const float4*)(bias + c);
  float4 o;
  o.x = fmaf(ri, acc.x, fmaf(invd, bf2f(sh.x) + bf2f(sl.x), bv.x));
  o.y = fmaf(ri, acc.y, fmaf(invd, bf2f(sh.y) + bf2f(sl.y), bv.y));
  o.z = fmaf(ri, acc.z, fmaf(invd, bf2f(sh.z) + bf2f(sl.z), bv.z));
  o.w = fmaf(ri, acc.w, fmaf(invd, bf2f(sh.w) + bf2f(sl.w), bv.w));
  *(float4*)(out + offi) = o;
}

// =================== persistent MFMA split-bf16 GEMM, LDS-staged W ===================
// Stage W hi+lo in LDS ONCE per block (512 blocks, 2/CU), then grid-stride over
// 64-row tiles with register double-buffered A-fragments: prefetch tile t+grid
// at loop top (program-order before tile t's stores -> in-place safe), compute t.
// acc += ah*wh + ah*wl + al*wh (al*wl ~2^-18 dropped) -> ~f32 accuracy.
// Fragment maps (m89/m91): A: m=lane&15,k=quad*8+j ; B: n=lane&15,k=quad*8+j ;
// D: row=quad*4+reg, col=lane&15.
template<int PRE, int BIAS, int RELU, int OSPLIT>
__global__ __launch_bounds__(256) void gemm_mfma(
    const u16* __restrict__ Ahi, const u16* __restrict__ Alo,
    const u16* __restrict__ Wgh, const u16* __restrict__ Wgl,
    const float* __restrict__ bias, const float* pre,
    float* outf, u16* ohi, u16* olo, int nrows, int ntiles)
{
  __shared__ u16 Wh[DIM * WLD];   // 34.8 KB
  __shared__ u16 Wl[DIM * WLD];   // 34.8 KB
  const int tid = threadIdx.x;
  const int wave = tid >> 6, lane = tid & 63;
  const int lr = lane & 15, quad = lane >> 4;

  for (int i = tid; i < DIM * DIM / 8; i += 256) {
    int cc = i >> 4, k8 = (i & 15) << 3;
    *(uint4*)&Wh[cc * WLD + k8] = ((const uint4*)Wgh)[i];
    *(uint4*)&Wl[cc * WLD + k8] = ((const uint4*)Wgl)[i];
  }
  __syncthreads();

  float bv[8];
#pragma unroll
  for (int ct = 0; ct < 8; ++ct) bv[ct] = BIAS ? bias[ct * 16 + lr] : 0.f;

  int t = blockIdx.x;
  v8s ch[4], cl[4];
  {
    int arow = t * 64 + wave * 16 + lr;
    if (arow >= nrows) arow = nrows - 1;
    const u16* ah = Ahi + (size_t)arow * DIM + quad * 8;
    const u16* al = Alo + (size_t)arow * DIM + quad * 8;
#pragma unroll
    for (int kk = 0; kk < 4; ++kk) {
      ch[kk] = *(const v8s*)(ah + kk * 32);
      cl[kk] = *(const v8s*)(al + kk * 32);
    }
  }

  while (t < ntiles) {
    const int tn = t + gridDim.x;
    v8s nh[4], nl[4];
    if (tn < ntiles) {               // prefetch next tile's A fragments
      int arow = tn * 64 + wave * 16 + lr;
      if (arow >= nrows) arow = nrows - 1;
      const u16* ah = Ahi + (size_t)arow * DIM + quad * 8;
      const u16* al = Alo + (size_t)arow * DIM + quad * 8;
#pragma unroll
      for (int kk = 0; kk < 4; ++kk) {
        nh[kk] = *(const v8s*)(ah + kk * 32);
        nl[kk] = *(const v8s*)(al + kk * 32);
      }
    }

    v4f acc[8];
#pragma unroll
    for (int ct = 0; ct < 8; ++ct) acc[ct] = (v4f){0.f, 0.f, 0.f, 0.f};
#pragma unroll
    for (int kk = 0; kk < 4; ++kk) {
#pragma unroll
      for (int ct = 0; ct < 8; ++ct) {
        const int wo = (ct * 16 + lr) * WLD + kk * 32 + quad * 8;
        v8s bh = *(const v8s*)&Wh[wo];
        v8s bl = *(const v8s*)&Wl[wo];
        acc[ct] = __builtin_amdgcn_mfma_f32_16x16x32_bf16(ch[kk], bh, acc[ct], 0, 0, 0);
        acc[ct] = __builtin_amdgcn_mfma_f32_16x16x32_bf16(ch[kk], bl, acc[ct], 0, 0, 0);
        acc[ct] = __builtin_amdgcn_mfma_f32_16x16x32_bf16(cl[kk], bh, acc[ct], 0, 0, 0);
      }
    }

    const int rowbase = t * 64 + wave * 16;
#pragma unroll
    for (int ct = 0; ct < 8; ++ct) {
      const int col = ct * 16 + lr;
#pragma unroll
      for (int rg = 0; rg < 4; ++rg) {
        int r = rowbase + quad * 4 + rg;
        if (r < nrows) {
          size_t off = (size_t)r * DIM + col;
          float v = acc[ct][rg] + bv[ct];
          if (PRE) v += pre[off];
          if (RELU) v = fmaxf(v, 0.f);
          if (OSPLIT) {
            u16 h, l;
            split2(v, h, l);
            ohi[off] = h;
            olo[off] = l;
          } else {
            outf[off] = v;
          }
        }
      }
    }

    t = tn;
#pragma unroll
    for (int kk = 0; kk < 4; ++kk) { ch[kk] = nh[kk]; cl[kk] = nl[kk]; }
  }
}

// =================== host ===================

extern "C" void kernel_launch(void* const* d_in, const int* in_sizes, int n_in,
                              void* d_out, int out_size, void* d_ws, size_t ws_size,
                              hipStream_t stream) {
  const float* emb = (const float*)d_in[0];
  const float* Wd  = (const float*)d_in[1];
  const float* bd  = (const float*)d_in[2];
  const float* Wg  = (const float*)d_in[3];
  const float* bg  = (const float*)d_in[4];
  const float* Wu  = (const float*)d_in[5];
  const float* bu  = (const float*)d_in[6];
  const int* d2u = (const int*)d_in[7];
  const int* sle = (const int*)d_in[8];
  const int* u2d = (const int*)d_in[9];
  const int E1 = in_sizes[7] / 2;   // 100000
  const int E2 = in_sizes[8] / 2;   // 600000
  const int E3 = in_sizes[9] / 2;   // 100000
  const int Etot = E1 + E2 + E3;
  const int N  = NNODES;
  const size_t nd = (size_t)N * DIM;

  u16* Phi  = (u16*)d_ws;
  u16* Plo  = Phi + nd;
  int* cnt  = (int*)(Plo + nd);    // [3N]
  int* fill = cnt + 3 * N;         // [3N]
  int* rs   = fill + 3 * N;        // [3N]
  int* eidx = rs + 3 * N;          // [Etot]
  float* rnorm = (float*)(eidx + Etot);
  int* bsum = (int*)(rnorm + N);
  u16* Whi = (u16*)(bsum + 1024);
  u16* Wlo = Whi + 3 * DIM * DIM;
  float* bufB = (float*)d_out;

  const int ntiles = (N + 63) / 64;               // 1563
  const int gemm_grid = 512;                      // persistent, 2 blocks/CU
  const int nscan = (3 * N + 1023) / 1024;        // 293
  const int ngather = (N * 32 + 255) / 256;       // 12500

  // ---- prep: W planes + unified CSR ----
  (void)hipMemsetAsync(cnt, 0, (size_t)6 * N * sizeof(int), stream);
  make_w_planes<<<(3 * DIM * DIM + 255) / 256, 256, 0, stream>>>(Wd, Wg, Wu, Whi, Wlo);
  count_all<<<(Etot + 255) / 256, 256, 0, stream>>>(d2u, sle, u2d, E1, E2, E3, cnt);
  make_rnorm<<<(N + 255) / 256, 256, 0, stream>>>(cnt + N, rnorm, N);
  scan_blocks<<<nscan, 256, 0, stream>>>(cnt, rs, bsum, 3 * N);
  scan_top<<<1, 256, 0, stream>>>(bsum, nscan);
  scan_add<<<nscan, 256, 0, stream>>>(rs, bsum, 3 * N);
  fill_all<<<(Etot + 255) / 256, 256, 0, stream>>>(d2u, sle, u2d, E1, E2, E3, rs, fill, eidx);

  // ---- stage A: agg1 = segment_mean(emb) -> planes ; x1 = relu(emb + agg1@Wd + bd) -> planes ----
  gather_mean_split<<<ngather, 256, 0, stream>>>(emb, rs, cnt, eidx, Phi, Plo, N);
  gemm_mfma<1, 1, 1, 1><<<gemm_grid, 256, 0, stream>>>(Phi, Plo, Whi, Wlo, bd, emb,
                                                       nullptr, Phi, Plo, N, ntiles);

  // ---- stage B: h = x1@Wg -> planes (in-place) ; x2 = gcn(h) -> d_out ----
  gemm_mfma<0, 0, 0, 1><<<gemm_grid, 256, 0, stream>>>(Phi, Plo, Whi + DIM * DIM,
                                                       Wlo + DIM * DIM, nullptr, nullptr,
                                                       nullptr, Phi, Plo, N, ntiles);
  gather_gcn<<<ngather, 256, 0, stream>>>(Phi, Plo, rs + N, cnt + N, eidx, rnorm, bg, bufB, N);

  // ---- stage C: agg2 = segment_mean(x2) -> planes ; out = relu(x2 + agg2@Wu + bu) ----
  gather_mean_split<<<ngather, 256, 0, stream>>>(bufB, rs + 2 * N, cnt + 2 * N, eidx, Phi, Plo, N);
  gemm_mfma<1, 1, 1, 0><<<gemm_grid, 256, 0, stream>>>(Phi, Plo, Whi + 2 * DIM * DIM,
                                                       Wlo + 2 * DIM * DIM, bu, bufB,
                                                       bufB, nullptr, nullptr, N, ntiles);
}

// Round 10
// 447.161 us; speedup vs baseline: 1.1325x; 1.1325x over previous
//
#include <hip/hip_runtime.h>
#include <cstdint>
#include <cstddef>

#define NNODES 100000
#define DIM 128
#define WLD 136   // LDS stride (u16) for W planes: bank step 4 -> 2-way (free, m136)

typedef unsigned short u16;
typedef __attribute__((ext_vector_type(8))) short v8s;
typedef __attribute__((ext_vector_type(4))) float v4f;

__device__ __forceinline__ float bf2f(u16 u) {
  union { uint32_t i; float f; } x; x.i = ((uint32_t)u) << 16; return x.f;
}
__device__ __forceinline__ u16 f2bf(float f) {
  union { float f; uint32_t i; } x; x.f = f;
  uint32_t r = x.i + 0x7fffu + ((x.i >> 16) & 1u);  // RNE
  return (u16)(r >> 16);
}
__device__ __forceinline__ void split2(float f, u16& hi, u16& lo) {
  u16 h = f2bf(f);
  float r = f - bf2f(h);     // exact
  hi = h;
  lo = f2bf(r);
}

// =================== unified CSR build (3 lists concatenated) ===================

__global__ void count_all(const int* __restrict__ d2u, const int* __restrict__ sle,
                          const int* __restrict__ u2d, int E1, int E2, int E3,
                          int* __restrict__ cnt) {
  int e = blockIdx.x * 256 + threadIdx.x;
  int idx;
  if (e < E1)            idx = d2u[E1 + e];
  else if (e < E1 + E2)  idx = NNODES + sle[E2 + (e - E1)];
  else if (e < E1 + E2 + E3) idx = 2 * NNODES + u2d[E3 + (e - E1 - E2)];
  else return;
  atomicAdd(&cnt[idx], 1);
}

__global__ void fill_all(const int* __restrict__ d2u, const int* __restrict__ sle,
                         const int* __restrict__ u2d, int E1, int E2, int E3,
                         const int* __restrict__ rs, int* __restrict__ fill,
                         int* __restrict__ eidx) {
  int e = blockIdx.x * 256 + threadIdx.x;
  int idx, src;
  if (e < E1)            { idx = d2u[E1 + e];                src = d2u[e]; }
  else if (e < E1 + E2)  { int q = e - E1; idx = NNODES + sle[E2 + q];     src = sle[q]; }
  else if (e < E1 + E2 + E3) { int q = e - E1 - E2; idx = 2 * NNODES + u2d[E3 + q]; src = u2d[q]; }
  else return;
  int p = rs[idx] + atomicAdd(&fill[idx], 1);
  eidx[p] = src;
}

__global__ void scan_blocks(const int* __restrict__ in, int* __restrict__ out,
                            int* __restrict__ bsum, int n) {
  __shared__ int wsum[4];
  const int tid = threadIdx.x;
  const int base = blockIdx.x * 1024 + tid * 4;
  int v0 = 0, v1 = 0, v2 = 0, v3 = 0;
  if (base + 0 < n) v0 = in[base + 0];
  if (base + 1 < n) v1 = in[base + 1];
  if (base + 2 < n) v2 = in[base + 2];
  if (base + 3 < n) v3 = in[base + 3];
  const int tsum = v0 + v1 + v2 + v3;
  const int lane = tid & 63, wid = tid >> 6;
  int x = tsum;
  for (int off = 1; off < 64; off <<= 1) {
    int y = __shfl_up(x, off, 64);
    if (lane >= off) x += y;
  }
  if (lane == 63) wsum[wid] = x;
  __syncthreads();
  int woff = 0;
  for (int w = 0; w < wid; ++w) woff += wsum[w];
  const int excl = woff + x - tsum;
  if (base + 0 < n) out[base + 0] = excl;
  if (base + 1 < n) out[base + 1] = excl + v0;
  if (base + 2 < n) out[base + 2] = excl + v0 + v1;
  if (base + 3 < n) out[base + 3] = excl + v0 + v1 + v2;
  if (tid == 255) bsum[blockIdx.x] = woff + x;
}

__global__ void scan_top(int* __restrict__ bsum, int nb) {
  __shared__ int tmp[1024];
  const int tid = threadIdx.x;
  for (int i = tid; i < 1024; i += 256) tmp[i] = (i < nb) ? bsum[i] : 0;
  __syncthreads();
  for (int off = 1; off < 1024; off <<= 1) {
    int vals[4];
#pragma unroll
    for (int j = 0; j < 4; ++j) { int i = tid + j * 256; vals[j] = (i >= off) ? tmp[i - off] : 0; }
    __syncthreads();
#pragma unroll
    for (int j = 0; j < 4; ++j) { int i = tid + j * 256; tmp[i] += vals[j]; }
    __syncthreads();
  }
  for (int i = tid; i < nb; i += 256) {
    int orig = bsum[i];
    bsum[i] = tmp[i] - orig;   // exclusive
  }
}

__global__ void scan_add(int* __restrict__ out, const int* __restrict__ bsum, int n) {
  const int b = blockIdx.x;
  const int off = bsum[b];
  const int base = b * 1024 + threadIdx.x * 4;
#pragma unroll
  for (int j = 0; j < 4; ++j)
    if (base + j < n) out[base + j] += off;
}

__global__ void make_rnorm(const int* __restrict__ cntB, float* __restrict__ rnorm, int n) {
  int i = blockIdx.x * 256 + threadIdx.x;
  if (i < n) rnorm[i] = rsqrtf((float)cntB[i] + 1.0f);
}

__global__ void make_w_planes(const float* __restrict__ W0, const float* __restrict__ W1,
                              const float* __restrict__ W2,
                              u16* __restrict__ Whi, u16* __restrict__ Wlo) {
  int i = blockIdx.x * 256 + threadIdx.x;
  if (i >= 3 * DIM * DIM) return;
  int m = i / (DIM * DIM);
  int idx = i - m * DIM * DIM;
  int k = idx >> 7, c = idx & 127;
  const float* W = (m == 0) ? W0 : ((m == 1) ? W1 : W2);
  u16 h, l;
  split2(W[idx], h, l);
  int o = m * DIM * DIM + c * DIM + k;
  Whi[o] = h;
  Wlo[o] = l;
}

// =================== gathers (32 threads / node, 4 cols each) ===================

__global__ void gather_mean_split(const float* __restrict__ x, const int* __restrict__ rs,
                                  const int* __restrict__ cnt, const int* __restrict__ eidx,
                                  u16* __restrict__ ohi, u16* __restrict__ olo, int n) {
  int gid = blockIdx.x * 256 + threadIdx.x;
  int i = gid >> 5;
  if (i >= n) return;
  int c = (gid & 31) << 2;
  int start = rs[i], m = cnt[i];
  float4 acc = {0.f, 0.f, 0.f, 0.f};
  int j = 0;
  for (; j + 1 < m; j += 2) {
    int s0 = eidx[start + j], s1 = eidx[start + j + 1];
    float4 v0 = *(const float4*)(x + (size_t)s0 * DIM + c);
    float4 v1 = *(const float4*)(x + (size_t)s1 * DIM + c);
    acc.x += v0.x + v1.x; acc.y += v0.y + v1.y;
    acc.z += v0.z + v1.z; acc.w += v0.w + v1.w;
  }
  if (j < m) {
    int s = eidx[start + j];
    float4 v = *(const float4*)(x + (size_t)s * DIM + c);
    acc.x += v.x; acc.y += v.y; acc.z += v.z; acc.w += v.w;
  }
  float inv = 1.0f / fmaxf((float)m, 1.0f);
  acc.x *= inv; acc.y *= inv; acc.z *= inv; acc.w *= inv;
  ushort4 sh, sl;
  split2(acc.x, sh.x, sl.x);
  split2(acc.y, sh.y, sl.y);
  split2(acc.z, sh.z, sl.z);
  split2(acc.w, sh.w, sl.w);
  size_t off = (size_t)i * DIM + c;
  *(ushort4*)(ohi + off) = sh;
  *(ushort4*)(olo + off) = sl;
}

__global__ void gather_gcn(const u16* __restrict__ hhi, const u16* __restrict__ hlo,
                           const int* __restrict__ rs, const int* __restrict__ cnt,
                           const int* __restrict__ eidx, const float* __restrict__ rnorm,
                           const float* __restrict__ bias, float* __restrict__ out, int n) {
  int gid = blockIdx.x * 256 + threadIdx.x;
  int i = gid >> 5;
  if (i >= n) return;
  int c = (gid & 31) << 2;
  int start = rs[i], m = cnt[i];
  float4 acc = {0.f, 0.f, 0.f, 0.f};
  int j = 0;
  for (; j + 1 < m; j += 2) {
    int s0 = eidx[start + j], s1 = eidx[start + j + 1];
    float r0 = rnorm[s0], r1 = rnorm[s1];
    size_t o0 = (size_t)s0 * DIM + c, o1 = (size_t)s1 * DIM + c;
    ushort4 h0 = *(const ushort4*)(hhi + o0), l0 = *(const ushort4*)(hlo + o0);
    ushort4 h1 = *(const ushort4*)(hhi + o1), l1 = *(const ushort4*)(hlo + o1);
    acc.x = fmaf(r0, bf2f(h0.x) + bf2f(l0.x), fmaf(r1, bf2f(h1.x) + bf2f(l1.x), acc.x));
    acc.y = fmaf(r0, bf2f(h0.y) + bf2f(l0.y), fmaf(r1, bf2f(h1.y) + bf2f(l1.y), acc.y));
    acc.z = fmaf(r0, bf2f(h0.z) + bf2f(l0.z), fmaf(r1, bf2f(h1.z) + bf2f(l1.z), acc.z));
    acc.w = fmaf(r0, bf2f(h0.w) + bf2f(l0.w), fmaf(r1, bf2f(h1.w) + bf2f(l1.w), acc.w));
  }
  if (j < m) {
    int s = eidx[start + j];
    float rn = rnorm[s];
    size_t off = (size_t)s * DIM + c;
    ushort4 vh = *(const ushort4*)(hhi + off);
    ushort4 vl = *(const ushort4*)(hlo + off);
    acc.x = fmaf(rn, bf2f(vh.x) + bf2f(vl.x), acc.x);
    acc.y = fmaf(rn, bf2f(vh.y) + bf2f(vl.y), acc.y);
    acc.z = fmaf(rn, bf2f(vh.z) + bf2f(vl.z), acc.z);
    acc.w = fmaf(rn, bf2f(vh.w) + bf2f(vl.w), acc.w);
  }
  float ri = rnorm[i];
  float invd = ri * ri;
  size_t offi = (size_t)i * DIM + c;
  ushort4 sh = *(const ushort4*)(hhi + offi);
  ushort4 sl = *(const ushort4*)(hlo + offi);
  float4 bv = *(const float4*)(bias + c);
  float4 o;
  o.x = fmaf(ri, acc.x, fmaf(invd, bf2f(sh.x) + bf2f(sl.x), bv.x));
  o.y = fmaf(ri, acc.y, fmaf(invd, bf2f(sh.y) + bf2f(sl.y), bv.y));
  o.z = fmaf(ri, acc.z, fmaf(invd, bf2f(sh.z) + bf2f(sl.z), bv.z));
  o.w = fmaf(ri, acc.w, fmaf(invd, bf2f(sh.w) + bf2f(sl.w), bv.w));
  *(float4*)(out + offi) = o;
}

// =================== MFMA split-bf16 GEMM, LDS-staged W, 512-thread blocks ===================
// MLP model (r8/r9): BW = waves/CU x in-flight/wave / latency. LDS is per-block,
// so 8-wave blocks double waves/CU at the same 69.6 KB W stage: 2 blocks/CU =
// 16 waves/CU (r8 had 4-wave blocks -> 8 waves/CU -> 1.33 TB/s; predict ~2x).
// No persistent loop / no reg double-buffer (r9: VGPR 192 halved waves -> 0.87 TB/s).
// Each wave: 16 rows x 128 cols; A-frags from global (issued before staging),
// B-frags from LDS. acc += ah*wh + ah*wl + al*wh (al*wl ~2^-18 dropped).
// Fragment maps (m89/m91): A: m=lane&15,k=quad*8+j ; B: n=lane&15,k=quad*8+j ;
// D: row=quad*4+reg, col=lane&15. In-place A->out safe: wave reads only the
// rows it writes.
template<int PRE, int BIAS, int RELU, int OSPLIT>
__global__ __launch_bounds__(512) void gemm_mfma(
    const u16* __restrict__ Ahi, const u16* __restrict__ Alo,
    const u16* __restrict__ Wgh, const u16* __restrict__ Wgl,
    const float* __restrict__ bias, const float* pre,
    float* outf, u16* ohi, u16* olo, int nrows)
{
  __shared__ u16 Wh[DIM * WLD];   // 34.8 KB
  __shared__ u16 Wl[DIM * WLD];   // 34.8 KB
  const int tid = threadIdx.x;
  const int wave = tid >> 6, lane = tid & 63;
  const int lr = lane & 15, quad = lane >> 4;
  const int rowbase = blockIdx.x * 128 + wave * 16;   // 8 waves x 16 rows

  // A fragments: issue before staging so they overlap the staging loads
  int arow = rowbase + lr;
  if (arow >= nrows) arow = nrows - 1;
  const u16* ah = Ahi + (size_t)arow * DIM + quad * 8;
  const u16* al = Alo + (size_t)arow * DIM + quad * 8;
  v8s afh[4], afl[4];
#pragma unroll
  for (int kk = 0; kk < 4; ++kk) {
    afh[kk] = *(const v8s*)(ah + kk * 32);
    afl[kk] = *(const v8s*)(al + kk * 32);
  }

  // stage W planes (coalesced b128 global reads, padded LDS writes)
  for (int i = tid; i < DIM * DIM / 8; i += 512) {
    int cc = i >> 4, k8 = (i & 15) << 3;
    *(uint4*)&Wh[cc * WLD + k8] = ((const uint4*)Wgh)[i];
    *(uint4*)&Wl[cc * WLD + k8] = ((const uint4*)Wgl)[i];
  }
  __syncthreads();

  v4f acc[8];
#pragma unroll
  for (int ct = 0; ct < 8; ++ct) acc[ct] = (v4f){0.f, 0.f, 0.f, 0.f};

#pragma unroll
  for (int kk = 0; kk < 4; ++kk) {
#pragma unroll
    for (int ct = 0; ct < 8; ++ct) {
      const int wo = (ct * 16 + lr) * WLD + kk * 32 + quad * 8;
      v8s bh = *(const v8s*)&Wh[wo];
      v8s bl = *(const v8s*)&Wl[wo];
      acc[ct] = __builtin_amdgcn_mfma_f32_16x16x32_bf16(afh[kk], bh, acc[ct], 0, 0, 0);
      acc[ct] = __builtin_amdgcn_mfma_f32_16x16x32_bf16(afh[kk], bl, acc[ct], 0, 0, 0);
      acc[ct] = __builtin_amdgcn_mfma_f32_16x16x32_bf16(afl[kk], bh, acc[ct], 0, 0, 0);
    }
  }

#pragma unroll
  for (int ct = 0; ct < 8; ++ct) {
    const int col = ct * 16 + lr;
    float bv = 0.f;
    if (BIAS) bv = bias[col];
#pragma unroll
    for (int rg = 0; rg < 4; ++rg) {
      int r = rowbase + quad * 4 + rg;
      if (r < nrows) {
        size_t off = (size_t)r * DIM + col;
        float v = acc[ct][rg] + bv;
        if (PRE) v += pre[off];
        if (RELU) v = fmaxf(v, 0.f);
        if (OSPLIT) {
          u16 h, l;
          split2(v, h, l);
          ohi[off] = h;
          olo[off] = l;
        } else {
          outf[off] = v;
        }
      }
    }
  }
}

// =================== host ===================

extern "C" void kernel_launch(void* const* d_in, const int* in_sizes, int n_in,
                              void* d_out, int out_size, void* d_ws, size_t ws_size,
                              hipStream_t stream) {
  const float* emb = (const float*)d_in[0];
  const float* Wd  = (const float*)d_in[1];
  const float* bd  = (const float*)d_in[2];
  const float* Wg  = (const float*)d_in[3];
  const float* bg  = (const float*)d_in[4];
  const float* Wu  = (const float*)d_in[5];
  const float* bu  = (const float*)d_in[6];
  const int* d2u = (const int*)d_in[7];
  const int* sle = (const int*)d_in[8];
  const int* u2d = (const int*)d_in[9];
  const int E1 = in_sizes[7] / 2;   // 100000
  const int E2 = in_sizes[8] / 2;   // 600000
  const int E3 = in_sizes[9] / 2;   // 100000
  const int Etot = E1 + E2 + E3;
  const int N  = NNODES;
  const size_t nd = (size_t)N * DIM;

  u16* Phi  = (u16*)d_ws;
  u16* Plo  = Phi + nd;
  int* cnt  = (int*)(Plo + nd);    // [3N]
  int* fill = cnt + 3 * N;         // [3N]
  int* rs   = fill + 3 * N;        // [3N]
  int* eidx = rs + 3 * N;          // [Etot]
  float* rnorm = (float*)(eidx + Etot);
  int* bsum = (int*)(rnorm + N);
  u16* Whi = (u16*)(bsum + 1024);
  u16* Wlo = Whi + 3 * DIM * DIM;
  float* bufB = (float*)d_out;

  const int gemm_blocks = (N + 127) / 128;        // 782 (128 rows / block)
  const int nscan = (3 * N + 1023) / 1024;        // 293
  const int ngather = (N * 32 + 255) / 256;       // 12500

  // ---- prep: W planes + unified CSR ----
  (void)hipMemsetAsync(cnt, 0, (size_t)6 * N * sizeof(int), stream);
  make_w_planes<<<(3 * DIM * DIM + 255) / 256, 256, 0, stream>>>(Wd, Wg, Wu, Whi, Wlo);
  count_all<<<(Etot + 255) / 256, 256, 0, stream>>>(d2u, sle, u2d, E1, E2, E3, cnt);
  make_rnorm<<<(N + 255) / 256, 256, 0, stream>>>(cnt + N, rnorm, N);
  scan_blocks<<<nscan, 256, 0, stream>>>(cnt, rs, bsum, 3 * N);
  scan_top<<<1, 256, 0, stream>>>(bsum, nscan);
  scan_add<<<nscan, 256, 0, stream>>>(rs, bsum, 3 * N);
  fill_all<<<(Etot + 255) / 256, 256, 0, stream>>>(d2u, sle, u2d, E1, E2, E3, rs, fill, eidx);

  // ---- stage A: agg1 = segment_mean(emb) -> planes ; x1 = relu(emb + agg1@Wd + bd) -> planes ----
  gather_mean_split<<<ngather, 256, 0, stream>>>(emb, rs, cnt, eidx, Phi, Plo, N);
  gemm_mfma<1, 1, 1, 1><<<gemm_blocks, 512, 0, stream>>>(Phi, Plo, Whi, Wlo, bd, emb,
                                                         nullptr, Phi, Plo, N);

  // ---- stage B: h = x1@Wg -> planes (in-place) ; x2 = gcn(h) -> d_out ----
  gemm_mfma<0, 0, 0, 1><<<gemm_blocks, 512, 0, stream>>>(Phi, Plo, Whi + DIM * DIM,
                                                         Wlo + DIM * DIM, nullptr, nullptr,
                                                         nullptr, Phi, Plo, N);
  gather_gcn<<<ngather, 256, 0, stream>>>(Phi, Plo, rs + N, cnt + N, eidx, rnorm, bg, bufB, N);

  // ---- stage C: agg2 = segment_mean(x2) -> planes ; out = relu(x2 + agg2@Wu + bu) ----
  gather_mean_split<<<ngather, 256, 0, stream>>>(bufB, rs + 2 * N, cnt + 2 * N, eidx, Phi, Plo, N);
  gemm_mfma<1, 1, 1, 0><<<gemm_blocks, 512, 0, stream>>>(Phi, Plo, Whi + 2 * DIM * DIM,
                                                         Wlo + 2 * DIM * DIM, bu, bufB,
                                                         bufB, nullptr, nullptr, N);
}